// Round 11
// baseline (4302.818 us; speedup 1.0000x reference)
//
#include <hip/hip_runtime.h>
#include <stdint.h>

#define GF_ACC   1
#define GF_BIAS  2
#define GF_RELU  8

#define BM 128
#define BN 64
#define BK 16

typedef short bf16x8 __attribute__((ext_vector_type(8)));
typedef float f32x4 __attribute__((ext_vector_type(4)));
typedef unsigned short u16x8 __attribute__((ext_vector_type(8)));

// ---------------- CSR build ----------------

__global__ void deg_count_kernel(const int* __restrict__ src, const int* __restrict__ dst,
                                 const float* __restrict__ ew,
                                 float* __restrict__ deg, int* __restrict__ cnt, int E)
{
    int e = blockIdx.x * blockDim.x + threadIdx.x;
    if (e < E) {
        int d = dst[e];
        atomicAdd(&deg[d], ew[e]);
        atomicAdd(&cnt[d], 1);
    }
}

__global__ void dis_kernel(const float* __restrict__ deg, float* __restrict__ dis, int n)
{
    int i = blockIdx.x * blockDim.x + threadIdx.x;
    if (i < n) {
        float d = deg[i];
        dis[i] = (d > 0.f) ? (1.0f / sqrtf(d)) : 0.f;
    }
}

__global__ __launch_bounds__(1024) void scan_kernel(int* __restrict__ cnt_cursor,
                                                    int* __restrict__ row_ptr, int n)
{
    __shared__ int wsum[16];
    __shared__ int s_carry;
    if (threadIdx.x == 0) s_carry = 0;
    __syncthreads();
    const int VT = 8;
    const int CHUNK = 1024 * VT;
    int lane = threadIdx.x & 63;
    int wid = threadIdx.x >> 6;
    for (int base = 0; base < n; base += CHUNK) {
        int v[VT];
        int idx0 = base + threadIdx.x * VT;
        int tsum = 0;
#pragma unroll
        for (int t = 0; t < VT; t++) {
            int i = idx0 + t;
            v[t] = (i < n) ? cnt_cursor[i] : 0;
            tsum += v[t];
        }
        int incl = tsum;
        for (int off = 1; off < 64; off <<= 1) {
            int t = __shfl_up(incl, off);
            if (lane >= off) incl += t;
        }
        if (lane == 63) wsum[wid] = incl;
        __syncthreads();
        if (wid == 0) {
            int wv = (lane < 16) ? wsum[lane] : 0;
            for (int off = 1; off < 16; off <<= 1) {
                int t = __shfl_up(wv, off);
                if (lane >= off) wv += t;
            }
            if (lane < 16) wsum[lane] = wv;
        }
        __syncthreads();
        int wave_off = (wid > 0) ? wsum[wid - 1] : 0;
        int excl = incl - tsum + wave_off + s_carry;
#pragma unroll
        for (int t = 0; t < VT; t++) {
            int i = idx0 + t;
            if (i < n) {
                cnt_cursor[i] = excl;
                row_ptr[i + 1] = excl + v[t];
            }
            excl += v[t];
        }
        __syncthreads();
        if (threadIdx.x == 0) s_carry += wsum[15];
        __syncthreads();
    }
    if (threadIdx.x == 0) row_ptr[0] = 0;
}

__global__ void scatter_kernel(const int* __restrict__ src, const int* __restrict__ dst,
                               const float* __restrict__ ew, const float* __restrict__ dis,
                               int* __restrict__ cursor, int2* __restrict__ e2, int E)
{
    int e = blockIdx.x * blockDim.x + threadIdx.x;
    if (e < E) {
        int s = src[e], d = dst[e];
        int pos = atomicAdd(&cursor[d], 1);
        float nw = dis[s] * ew[e] * dis[d];
        e2[pos] = make_int2(s, __float_as_int(nw));
    }
}

// ---------------- propagation ----------------

__global__ __launch_bounds__(256) void prop1(const float* __restrict__ xv, const float* __restrict__ z,
                                             float* __restrict__ y, const int* __restrict__ rp,
                                             const int2* __restrict__ e2, int n, int mode)
{
    int node = blockIdx.x * 64 + (threadIdx.x >> 2);
    if (node >= n) return;
    int g = threadIdx.x & 3;
    int e0 = rp[node], e1 = rp[node + 1];
    float acc = 0.f;
    int e = e0 + g;
    for (; e + 4 < e1; e += 8) {
        int2 qa = e2[e];
        int2 qb = e2[e + 4];
        acc += __int_as_float(qa.y) * xv[qa.x];
        acc += __int_as_float(qb.y) * xv[qb.x];
    }
    if (e < e1) {
        int2 q = e2[e];
        acc += __int_as_float(q.y) * xv[q.x];
    }
    acc += __shfl_xor(acc, 1);
    acc += __shfl_xor(acc, 2);
    if (g == 0) {
        if (z) acc += z[node];
        if (mode == 1) acc = 1.0f / (1.0f + expf(-acc));
        y[node] = acc;
    }
}

// propw2: LPN lanes per node, each lane owns one float4 column group and loops edges 8-deep.
template<int LPN, int C4, bool HASZ, bool RELU>
__global__ __launch_bounds__(256) void propw2(const float* __restrict__ X, int xstr,
                                              const float* __restrict__ Z, int zstr,
                                              float* __restrict__ Y, int ystr,
                                              const int* __restrict__ rp,
                                              const int2* __restrict__ e2, int n)
{
    const int NPB = 256 / LPN;
    int node = blockIdx.x * NPB + threadIdx.x / LPN;
    if (node >= n) return;
    int c4 = threadIdx.x % LPN;
    bool colok = (c4 < C4);
    int cq = colok ? c4 : 0;
    int e0 = rp[node], e1 = rp[node + 1];
    float ax = 0.f, ay = 0.f, az = 0.f, aw = 0.f;
    int e = e0;
    for (; e + 8 <= e1; e += 8) {
        int2 q[8];
#pragma unroll
        for (int u = 0; u < 8; u++) q[u] = e2[e + u];
        float4 xq[8];
#pragma unroll
        for (int u = 0; u < 8; u++)
            xq[u] = *(const float4*)(X + (size_t)q[u].x * xstr + 4 * cq);
#pragma unroll
        for (int u = 0; u < 8; u++) {
            float wv = __int_as_float(q[u].y);
            ax += wv * xq[u].x; ay += wv * xq[u].y;
            az += wv * xq[u].z; aw += wv * xq[u].w;
        }
    }
    if (e < e1) {
#pragma unroll
        for (int u = 0; u < 8; u++) {
            int eid = e + u;
            int2 q = (eid < e1) ? e2[eid] : make_int2(0, 0);
            float4 xq = *(const float4*)(X + (size_t)q.x * xstr + 4 * cq);
            float wv = __int_as_float(q.y);
            ax += wv * xq.x; ay += wv * xq.y; az += wv * xq.z; aw += wv * xq.w;
        }
    }
    if (colok) {
        if (HASZ) {
            float4 zq = *(const float4*)(Z + (size_t)node * zstr + 4 * c4);
            ax += zq.x; ay += zq.y; az += zq.z; aw += zq.w;
        }
        if (RELU) {
            ax = fmaxf(ax, 0.f); ay = fmaxf(ay, 0.f);
            az = fmaxf(az, 0.f); aw = fmaxf(aw, 0.f);
        }
        float4 o = { ax, ay, az, aw };
        *(float4*)(Y + (size_t)node * ystr + 4 * c4) = o;
    }
}

// ---------------- fp32 GEMM (L1/L5 odd shapes; R3-proven config) ----------------

__global__ __launch_bounds__(256) void gemm2(
    const float* __restrict__ X, int x_sn, int x_sk,
    const float* __restrict__ W, int w_sk, int w_sc,
    const float* __restrict__ bias,
    float* __restrict__ out, int o_sn, int o_sc,
    int M, int K, int NC, int flags, int bias_cols)
{
    __shared__ float Xs[BK][BM + 4];
    __shared__ float Ws[BK][BN];
    int tid = threadIdx.x;
    int bm = blockIdx.x * BM;
    int bn = blockIdx.y * BN;
    int tx = tid & 15, ty = tid >> 4;
    float acc[8][4] = {};
    int xk = tid & 15, xm = tid >> 4;
    int wc = tid & 63, wk4 = tid >> 6;
    int vr = tid >> 2;
    int vc = (tid & 3) * 4;
    int wvk = tid >> 4;
    int wvc = (tid & 15) * 4;
    bool xvec = (x_sk == 1) && ((x_sn & 3) == 0) && (bm + BM <= M);
    bool wvec = (w_sc == 1) && ((w_sk & 3) == 0) && (bn + BN <= NC);
    for (int k0 = 0; k0 < K; k0 += BK) {
        bool fullk = (k0 + BK <= K);
        if (xvec && fullk) {
#pragma unroll
            for (int h = 0; h < 2; h++) {
                int m = vr + 64 * h;
                const float4 q = *(const float4*)(X + (size_t)(bm + m) * x_sn + k0 + vc);
                Xs[vc + 0][m] = q.x; Xs[vc + 1][m] = q.y;
                Xs[vc + 2][m] = q.z; Xs[vc + 3][m] = q.w;
            }
        } else {
#pragma unroll
            for (int r = 0; r < 8; r++) {
                int m = xm + 16 * r;
                int gm = bm + m, gk = k0 + xk;
                Xs[xk][m] = (gm < M && gk < K) ? X[(size_t)gm * x_sn + (size_t)gk * x_sk] : 0.f;
            }
        }
        if (wvec && fullk) {
            *(float4*)&Ws[wvk][wvc] = *(const float4*)(W + (size_t)(k0 + wvk) * w_sk + bn + wvc);
        } else {
#pragma unroll
            for (int r = 0; r < 4; r++) {
                int kk = wk4 + 4 * r;
                int gk = k0 + kk, gc = bn + wc;
                Ws[kk][wc] = (gk < K && gc < NC) ? W[(size_t)gk * w_sk + (size_t)gc * w_sc] : 0.f;
            }
        }
        __syncthreads();
#pragma unroll
        for (int kk = 0; kk < BK; kk++) {
            float xv[8], wv[4];
#pragma unroll
            for (int i = 0; i < 8; i++) xv[i] = Xs[kk][ty * 8 + i];
#pragma unroll
            for (int j = 0; j < 4; j++) wv[j] = Ws[kk][tx * 4 + j];
#pragma unroll
            for (int i = 0; i < 8; i++)
#pragma unroll
                for (int j = 0; j < 4; j++)
                    acc[i][j] += xv[i] * wv[j];
        }
        __syncthreads();
    }
    bool ovec = (o_sc == 1) && ((o_sn & 3) == 0) && (bn + tx * 4 + 3 < NC);
#pragma unroll
    for (int i = 0; i < 8; i++) {
        int gm = bm + ty * 8 + i;
        if (gm >= M) continue;
        if (ovec) {
            float* op = out + (size_t)gm * o_sn + bn + tx * 4;
            float4 v = { acc[i][0], acc[i][1], acc[i][2], acc[i][3] };
            if (flags & GF_ACC) {
                float4 o = *(const float4*)op;
                v.x += o.x; v.y += o.y; v.z += o.z; v.w += o.w;
            }
            if (flags & GF_BIAS) {
#pragma unroll
                for (int j = 0; j < 4; j++) {
                    int gc = bn + tx * 4 + j;
                    if (gc < bias_cols) (&v.x)[j] += bias[gc];
                }
            }
            if (flags & GF_RELU) {
                v.x = fmaxf(v.x, 0.f); v.y = fmaxf(v.y, 0.f);
                v.z = fmaxf(v.z, 0.f); v.w = fmaxf(v.w, 0.f);
            }
            *(float4*)op = v;
        } else {
#pragma unroll
            for (int j = 0; j < 4; j++) {
                int gc = bn + tx * 4 + j;
                if (gc >= NC) continue;
                size_t oi = (size_t)gm * o_sn + (size_t)gc * o_sc;
                float v = acc[i][j];
                if (flags & GF_ACC)  v += out[oi];
                if ((flags & GF_BIAS) && gc < bias_cols) v += bias[gc];
                if (flags & GF_RELU) v = fmaxf(v, 0.f);
                out[oi] = v;
            }
        }
    }
}

// ---------------- 3-term bf16 split + fragment-ordered W packing ----------------
// Packed layout: idx = (((nb*ksteps + ks)*8 + nt)*3 + plane)*512 + lane*8 + j
// where lane = kq*16 + r, n = nb*128 + nt*16 + r, k = ks*32 + kq*8 + j.
// A wave's B-fragment load is 64 lanes x 16B contiguous (1KB, coalesced, L2-broadcast).

__device__ __forceinline__ void bf16_split3(float v, unsigned short* h,
                                            unsigned short* m, unsigned short* l)
{
    unsigned u = __float_as_uint(v);
    unsigned uh = (u + 0x8000u) & 0xFFFF0000u;
    float fh = __uint_as_float(uh);
    float r1 = v - fh;
    unsigned u1 = __float_as_uint(r1);
    unsigned um = (u1 + 0x8000u) & 0xFFFF0000u;
    float fm = __uint_as_float(um);
    float r2 = r1 - fm;
    unsigned ul = (__float_as_uint(r2) + 0x8000u) & 0xFFFF0000u;
    *h = (unsigned short)(uh >> 16);
    *m = (unsigned short)(um >> 16);
    *l = (unsigned short)(ul >> 16);
}

__device__ __forceinline__ void pack_write(unsigned short* __restrict__ wpk,
                                           int ksteps, int n, int k, float v)
{
    unsigned short h8, m8, l8;
    bf16_split3(v, &h8, &m8, &l8);
    int nb = n >> 7, nn = n & 127;
    int nt = nn >> 4, r = nn & 15;
    int ks = k >> 5, kq = (k >> 3) & 3, j = k & 7;
    int ln = kq * 16 + r;
    size_t base = ((((size_t)nb * ksteps + ks) * 8 + nt) * 3) * 512 + ln * 8 + j;
    wpk[base] = h8;
    wpk[base + 512] = m8;
    wpk[base + 1024] = l8;
}

// W [hops, Cin, Cout] -> packed; k = hop_slot*slot + c, n = cout
__global__ void splitW_stack(const float* __restrict__ Wsrc, int hop0, int H,
                             int Cin, int Cout, int slot, int Kp, int NCp, int ksteps,
                             unsigned short* __restrict__ wpk)
{
    int t = blockIdx.x * blockDim.x + threadIdx.x;
    if (t >= NCp * Kp) return;
    int k = t % Kp, n = t / Kp;
    int j = k / slot, c = k % slot;
    float v = (n < Cout && j < H && c < Cin)
        ? Wsrc[((size_t)(hop0 + j) * Cin + c) * Cout + n] : 0.f;
    pack_write(wpk, ksteps, n, k, v);
}

// W4 [21, 200, 80] -> packed; n = (hop-k_lo)*80 + co, k = cin
__global__ void splitW_horner(const float* __restrict__ W4, int k_lo, int nb,
                              int Kp, int NCp, int ksteps,
                              unsigned short* __restrict__ wpk)
{
    int t = blockIdx.x * blockDim.x + threadIdx.x;
    if (t >= NCp * Kp) return;
    int k = t % Kp, n = t / Kp;
    float v = 0.f;
    if (k < 200 && n < nb * 80) {
        int hop = k_lo + n / 80, co = n % 80;
        v = W4[(size_t)hop * 16000 + (size_t)k * 80 + co];
    }
    pack_write(wpk, ksteps, n, k, v);
}

// ---------------- MFMA GEMM v2: no LDS, no barriers ----------------
// One wave per block; wave tile 16 rows x 128 cols (8 n-tiles of 16x16x32).
// A direct from global (line-coalesced: 16 rows x 128B); B from packed W
// (1KB contiguous per fragment, L2-broadcast). 3-term split, 6 products.

__global__ __launch_bounds__(64) void gemm_mfma2(
    const float* __restrict__ X, int x_sn,
    const unsigned short* __restrict__ Wpk, int ksteps,
    const float* __restrict__ bias,
    float* __restrict__ out, int o_sn,
    int M, int NC, int flags, int bias_cols)
{
    int lane = threadIdx.x;
    int r = lane & 15, q = lane >> 4;
    int bm = blockIdx.x * 16;
    int nb = blockIdx.y;
    int bn = nb * 128;
    f32x4 acc[8];
#pragma unroll
    for (int b = 0; b < 8; b++) acc[b] = (f32x4){0.f, 0.f, 0.f, 0.f};
    const float* xrow = X + (size_t)(bm + r) * x_sn + q * 8;
    const unsigned short* wbase = Wpk + (size_t)nb * ksteps * (8 * 3 * 512) + lane * 8;
    for (int ks = 0; ks < ksteps; ks++) {
        float4 fa = *(const float4*)(xrow + ks * 32);
        float4 fb = *(const float4*)(xrow + ks * 32 + 4);
        const unsigned short* wk = wbase + (size_t)ks * (8 * 3 * 512);
        float vf[8] = { fa.x, fa.y, fa.z, fa.w, fb.x, fb.y, fb.z, fb.w };
        bf16x8 ah, am, al;
#pragma unroll
        for (int j = 0; j < 8; j++) {
            float v = vf[j];
            unsigned u = __float_as_uint(v);
            unsigned uh = u & 0xFFFF0000u;
            float r1 = v - __uint_as_float(uh);
            unsigned u1 = __float_as_uint(r1);
            unsigned um = u1 & 0xFFFF0000u;
            float r2 = r1 - __uint_as_float(um);
            ah[j] = (short)(uh >> 16);
            am[j] = (short)(um >> 16);
            al[j] = (short)(__float_as_uint(r2) >> 16);
        }
#pragma unroll
        for (int nt = 0; nt < 8; nt++) {
            bf16x8 bh  = *(const bf16x8*)(wk + (nt * 3 + 0) * 512);
            bf16x8 bm2 = *(const bf16x8*)(wk + (nt * 3 + 1) * 512);
            bf16x8 bl  = *(const bf16x8*)(wk + (nt * 3 + 2) * 512);
            acc[nt] = __builtin_amdgcn_mfma_f32_16x16x32_bf16(al, bh, acc[nt], 0, 0, 0);
            acc[nt] = __builtin_amdgcn_mfma_f32_16x16x32_bf16(ah, bl, acc[nt], 0, 0, 0);
            acc[nt] = __builtin_amdgcn_mfma_f32_16x16x32_bf16(am, bm2, acc[nt], 0, 0, 0);
            acc[nt] = __builtin_amdgcn_mfma_f32_16x16x32_bf16(am, bh, acc[nt], 0, 0, 0);
            acc[nt] = __builtin_amdgcn_mfma_f32_16x16x32_bf16(ah, bm2, acc[nt], 0, 0, 0);
            acc[nt] = __builtin_amdgcn_mfma_f32_16x16x32_bf16(ah, bh, acc[nt], 0, 0, 0);
        }
    }
#pragma unroll
    for (int i = 0; i < 4; i++) {
        int gm = bm + q * 4 + i;
        if (gm >= M) continue;
#pragma unroll
        for (int nt = 0; nt < 8; nt++) {
            int gc = bn + nt * 16 + r;
            if (gc >= NC) continue;
            size_t oi = (size_t)gm * o_sn + gc;
            float v = acc[nt][i];
            if (flags & GF_ACC)  v += out[oi];
            if ((flags & GF_BIAS) && gc < bias_cols) v += bias[gc];
            if (flags & GF_RELU) v = fmaxf(v, 0.f);
            out[oi] = v;
        }
    }
}

// ---------------- launch ----------------

extern "C" void kernel_launch(void* const* d_in, const int* in_sizes, int n_in,
                              void* d_out, int out_size, void* d_ws, size_t ws_size,
                              hipStream_t stream)
{
    const int N = 50000, E = 800000, K = 20;
    const float* x  = (const float*)d_in[0];
    const int*   ei = (const int*)d_in[1];
    const float* ew = (const float*)d_in[2];
    const float* Wl[5]; const float* bl[5];
    for (int l = 0; l < 5; l++) { Wl[l] = (const float*)d_in[3 + 2 * l]; bl[l] = (const float*)d_in[4 + 2 * l]; }
    const int* src = ei;
    const int* dst = ei + E;
    (void)in_sizes; (void)n_in; (void)out_size;

    uintptr_t base = (uintptr_t)d_ws;
    uintptr_t cur = base;
    auto alloc = [&](size_t bytes) -> char* {
        uintptr_t q = (cur + 255) & ~(uintptr_t)255;
        cur = q + bytes;
        return (char*)q;
    };
    float* deg    = (float*)alloc((size_t)N * 4);
    float* dis    = (float*)alloc((size_t)N * 4);
    int*   rowptr = (int*)alloc((size_t)(N + 1) * 4);
    int*   cursor = (int*)alloc((size_t)N * 4);
    int2*  e2     = (int2*)alloc((size_t)E * 8);
    float* Zb     = (float*)alloc((size_t)(K + 1) * N * 4);  // [21, N] hop-major
    float* ya     = (float*)alloc((size_t)N * 4);
    float* yb     = (float*)alloc((size_t)N * 4);
    float* h1     = (float*)alloc((size_t)N * 64 * 4);   // stride 64 (padded, gathered)
    float* h2     = (float*)alloc((size_t)N * 100 * 4);
    float* h3     = (float*)alloc((size_t)N * 200 * 4);
    float* h4     = (float*)alloc((size_t)N * 80 * 4);
    float* Ra     = (float*)alloc((size_t)N * 96 * 4);   // stride 96 (padded, gathered)
    float* Rb     = (float*)alloc((size_t)N * 96 * 4);

    size_t used = (size_t)(cur - base);
    size_t reserve = (size_t)8 << 20;
    size_t avail = (ws_size > used + reserve) ? (ws_size - used - reserve) : 0;
    size_t cap = (size_t)N * 2000 * 4;
    size_t arena_bytes = avail < cap ? avail : cap;
    float* Sb = (float*)alloc(arena_bytes);
    unsigned short* Wpk = (unsigned short*)alloc((size_t)4 << 20);
    const size_t cacheCap = (size_t)128 << 20;
    size_t lim = arena_bytes < cacheCap ? arena_bytes : cacheCap;
    auto clampH = [&](int slotw, int hi) {
        long h = (long)(lim / ((size_t)N * slotw * 4));
        if (h < 1) h = 1;
        if (h > hi) h = hi;
        return (int)h;
    };
    const int H2s = clampH(64, K);       // -> 10
    const int H3s = clampH(100, K);      // -> 6
    const int B4s = clampH(80, K + 1);   // -> 8
    const int rowstr2 = H2s * 64;
    const int rowstr3 = H3s * 100;
    const int rowstr4 = B4s * 80;

    // ---- CSR build
    hipMemsetAsync(deg, 0, (size_t)N * 4, stream);
    hipMemsetAsync(cursor, 0, (size_t)N * 4, stream);
    deg_count_kernel<<<(E + 255) / 256, 256, 0, stream>>>(src, dst, ew, deg, cursor, E);
    dis_kernel<<<(N + 255) / 256, 256, 0, stream>>>(deg, dis, N);
    scan_kernel<<<1, 1024, 0, stream>>>(cursor, rowptr, N);
    scatter_kernel<<<(E + 255) / 256, 256, 0, stream>>>(src, dst, ew, dis, cursor, e2, E);

    const int PB = (N + 63) / 64;
    const int P16 = (N + 15) / 16;
    const int P32 = (N + 7) / 8;
    const int GMX = (N + BM - 1) / BM;
    const int MT = N / 16;               // 3125 wave-blocks (N divisible by 16)
    auto gyf = [](int NC) { return (NC + BN - 1) / BN; };

    // ---- Layer 1 (1 -> 60): width-1 chain into Zb, one fp32 GEMM K=21
    hipMemcpyAsync(Zb, x, (size_t)N * 4, hipMemcpyDeviceToDevice, stream);
    for (int k = 1; k <= K; k++)
        prop1<<<PB, 256, 0, stream>>>(Zb + (size_t)(k - 1) * N, nullptr, Zb + (size_t)k * N,
                                      rowptr, e2, N, 0);
    gemm2<<<dim3(GMX, gyf(60)), 256, 0, stream>>>(Zb, 1, N, Wl[0], 60, 1, bl[0],
                                                  h1, 64, 1, N, K + 1, 60, GF_BIAS | GF_RELU, 60);

    // ---- Layer 2 (60 -> 100): h0 via MFMA (Kp=64), hop-batched stack + MFMA
    splitW_stack<<<(128 * 64 + 255) / 256, 256, 0, stream>>>(Wl[1], 0, 1, 60, 100, 64,
                                                             64, 128, 2, Wpk);
    gemm_mfma2<<<dim3(MT, 1), 64, 0, stream>>>(h1, 64, Wpk, 2,
        bl[1], h2, 100, N, 100, GF_BIAS, 100);
    {
        int done = 0;
        const float* prevp = h1; int prevstr = 64;
        while (done < K) {
            int H = (K - done < H2s) ? (K - done) : H2s;
            for (int j = 0; j < H; j++) {
                float* dstp = Sb + j * 64;
                propw2<16, 15, false, false><<<P16, 256, 0, stream>>>(prevp, prevstr, nullptr, 0,
                    dstp, rowstr2, rowptr, e2, N);
                prevp = dstp; prevstr = rowstr2;
            }
            int Kg = H * 64;                   // multiple of 32
            int ksteps = Kg / 32;
            int tot = 128 * Kg;
            splitW_stack<<<(tot + 255) / 256, 256, 0, stream>>>(Wl[1], 1 + done, H, 60, 100, 64,
                                                               Kg, 128, ksteps, Wpk);
            bool last = (done + H == K);
            gemm_mfma2<<<dim3(MT, 1), 64, 0, stream>>>(Sb, rowstr2, Wpk, ksteps,
                nullptr, h2, 100, N, 100, GF_ACC | (last ? GF_RELU : 0), 0);
            done += H;
        }
    }

    // ---- Layer 3 (100 -> 200): h0 via MFMA (Kp=128), hop-batched stack + MFMA
    splitW_stack<<<(256 * 128 + 255) / 256, 256, 0, stream>>>(Wl[2], 0, 1, 100, 200, 128,
                                                              128, 256, 4, Wpk);
    gemm_mfma2<<<dim3(MT, 2), 64, 0, stream>>>(h2, 100, Wpk, 4,
        bl[2], h3, 200, N, 200, GF_BIAS, 200);
    {
        int done = 0;
        const float* prevp = h2; int prevstr = 100;
        while (done < K) {
            int H = (K - done < H3s) ? (K - done) : H3s;
            for (int j = 0; j < H; j++) {
                float* dstp = Sb + j * 100;
                propw2<32, 25, false, false><<<P32, 256, 0, stream>>>(prevp, prevstr, nullptr, 0,
                    dstp, rowstr3, rowptr, e2, N);
                prevp = dstp; prevstr = rowstr3;
            }
            int Kg = H * 100;
            int Kp = (Kg + 31) & ~31;
            int ksteps = Kp / 32;
            int tot = 256 * Kp;
            splitW_stack<<<(tot + 255) / 256, 256, 0, stream>>>(Wl[2], 1 + done, H, 100, 200, 100,
                                                               Kp, 256, ksteps, Wpk);
            bool last = (done + H == K);
            gemm_mfma2<<<dim3(MT, 2), 64, 0, stream>>>(Sb, rowstr3, Wpk, ksteps,
                nullptr, h3, 200, N, 200, GF_ACC | (last ? GF_RELU : 0), 0);
            done += H;
        }
    }

    // ---- Layer 4 (200 -> 80): batched Z pre-GEMM (MFMA) + Horner width-80
    {
        const float* curR = nullptr; int curstr = 0;
        int k_hi = K;
        while (k_hi >= 0) {
            int k_lo = k_hi - B4s + 1; if (k_lo < 0) k_lo = 0;
            int nb = k_hi - k_lo + 1;
            int NCpb = (nb * 80 + 127) / 128;
            int NCp = NCpb * 128;
            int tot = NCp * 224;
            splitW_horner<<<(tot + 255) / 256, 256, 0, stream>>>(Wl[3], k_lo, nb,
                                                                 224, NCp, 7, Wpk);
            gemm_mfma2<<<dim3(MT, NCpb), 64, 0, stream>>>(h3, 200, Wpk, 7,
                bl[3], Sb, rowstr4, N, nb * 80, (k_lo == 0) ? GF_BIAS : 0, 80);
            int kstart;
            if (k_hi == K) { curR = Sb + (size_t)(K - k_lo) * 80; curstr = rowstr4; kstart = K - 1; }
            else kstart = k_hi;
            for (int k = kstart; k >= k_lo; k--) {
                const float* Zp = Sb + (size_t)(k - k_lo) * 80;
                if (k == 0) {
                    propw2<32, 20, true, true><<<P32, 256, 0, stream>>>(curR, curstr, Zp, rowstr4,
                        h4, 80, rowptr, e2, N);
                } else {
                    float* o = (k & 1) ? Ra : Rb;
                    propw2<32, 20, true, false><<<P32, 256, 0, stream>>>(curR, curstr, Zp, rowstr4,
                        o, 96, rowptr, e2, N);
                    curR = o; curstr = 96;
                }
            }
            k_hi = k_lo - 1;
        }
    }

    // ---- Layer 5 (80 -> 1): Z5 [21, N] hop-major, Horner width-1 with sigmoid
    gemm2<<<dim3(GMX, gyf(21)), 256, 0, stream>>>(h4, 80, 1, Wl[4], 1, 80, bl[4],
                                                  Zb, 1, N, N, 80, K + 1, GF_BIAS, 1);
    const float* cur5 = Zb + (size_t)K * N;
    float* outp = (float*)d_out;
    for (int k = K - 1; k >= 0; k--) {
        float* o = (k == 0) ? outp : ((k & 1) ? ya : yb);
        prop1<<<PB, 256, 0, stream>>>(cur5, Zb + (size_t)k * N, o,
                                      rowptr, e2, N, (k == 0) ? 1 : 0);
        cur5 = o;
    }
}

// Round 12
// 4291.935 us; speedup vs baseline: 1.0025x; 1.0025x over previous
//
#include <hip/hip_runtime.h>
#include <stdint.h>

#define GF_ACC   1
#define GF_BIAS  2
#define GF_RELU  8

#define BM 128
#define BN 64
#define BK 16

typedef short bf16x8 __attribute__((ext_vector_type(8)));
typedef float f32x4 __attribute__((ext_vector_type(4)));
typedef unsigned short u16x8 __attribute__((ext_vector_type(8)));

// ---------------- CSR build ----------------

__global__ void deg_count_kernel(const int* __restrict__ src, const int* __restrict__ dst,
                                 const float* __restrict__ ew,
                                 float* __restrict__ deg, int* __restrict__ cnt, int E)
{
    int e = blockIdx.x * blockDim.x + threadIdx.x;
    if (e < E) {
        int d = dst[e];
        atomicAdd(&deg[d], ew[e]);
        atomicAdd(&cnt[d], 1);
    }
}

__global__ void dis_kernel(const float* __restrict__ deg, float* __restrict__ dis, int n)
{
    int i = blockIdx.x * blockDim.x + threadIdx.x;
    if (i < n) {
        float d = deg[i];
        dis[i] = (d > 0.f) ? (1.0f / sqrtf(d)) : 0.f;
    }
}

__global__ __launch_bounds__(1024) void scan_kernel(int* __restrict__ cnt_cursor,
                                                    int* __restrict__ row_ptr, int n)
{
    __shared__ int wsum[16];
    __shared__ int s_carry;
    if (threadIdx.x == 0) s_carry = 0;
    __syncthreads();
    const int VT = 8;
    const int CHUNK = 1024 * VT;
    int lane = threadIdx.x & 63;
    int wid = threadIdx.x >> 6;
    for (int base = 0; base < n; base += CHUNK) {
        int v[VT];
        int idx0 = base + threadIdx.x * VT;
        int tsum = 0;
#pragma unroll
        for (int t = 0; t < VT; t++) {
            int i = idx0 + t;
            v[t] = (i < n) ? cnt_cursor[i] : 0;
            tsum += v[t];
        }
        int incl = tsum;
        for (int off = 1; off < 64; off <<= 1) {
            int t = __shfl_up(incl, off);
            if (lane >= off) incl += t;
        }
        if (lane == 63) wsum[wid] = incl;
        __syncthreads();
        if (wid == 0) {
            int wv = (lane < 16) ? wsum[lane] : 0;
            for (int off = 1; off < 16; off <<= 1) {
                int t = __shfl_up(wv, off);
                if (lane >= off) wv += t;
            }
            if (lane < 16) wsum[lane] = wv;
        }
        __syncthreads();
        int wave_off = (wid > 0) ? wsum[wid - 1] : 0;
        int excl = incl - tsum + wave_off + s_carry;
#pragma unroll
        for (int t = 0; t < VT; t++) {
            int i = idx0 + t;
            if (i < n) {
                cnt_cursor[i] = excl;
                row_ptr[i + 1] = excl + v[t];
            }
            excl += v[t];
        }
        __syncthreads();
        if (threadIdx.x == 0) s_carry += wsum[15];
        __syncthreads();
    }
    if (threadIdx.x == 0) row_ptr[0] = 0;
}

__global__ void scatter_kernel(const int* __restrict__ src, const int* __restrict__ dst,
                               const float* __restrict__ ew, const float* __restrict__ dis,
                               int* __restrict__ cursor, int2* __restrict__ e2, int E)
{
    int e = blockIdx.x * blockDim.x + threadIdx.x;
    if (e < E) {
        int s = src[e], d = dst[e];
        int pos = atomicAdd(&cursor[d], 1);
        float nw = dis[s] * ew[e] * dis[d];
        e2[pos] = make_int2(s, __float_as_int(nw));
    }
}

// ---------------- propagation ----------------

__global__ __launch_bounds__(256) void prop1(const float* __restrict__ xv, const float* __restrict__ z,
                                             float* __restrict__ y, const int* __restrict__ rp,
                                             const int2* __restrict__ e2, int n, int mode)
{
    int node = blockIdx.x * 64 + (threadIdx.x >> 2);
    if (node >= n) return;
    int g = threadIdx.x & 3;
    int e0 = rp[node], e1 = rp[node + 1];
    float acc = 0.f;
    int e = e0 + g;
    for (; e + 4 < e1; e += 8) {
        int2 qa = e2[e];
        int2 qb = e2[e + 4];
        acc += __int_as_float(qa.y) * xv[qa.x];
        acc += __int_as_float(qb.y) * xv[qb.x];
    }
    if (e < e1) {
        int2 q = e2[e];
        acc += __int_as_float(q.y) * xv[q.x];
    }
    acc += __shfl_xor(acc, 1);
    acc += __shfl_xor(acc, 2);
    if (g == 0) {
        if (z) acc += z[node];
        if (mode == 1) acc = 1.0f / (1.0f + expf(-acc));
        y[node] = acc;
    }
}

// propw2: LPN lanes per node, each lane owns one float4 column group and loops edges 8-deep.
template<int LPN, int C4, bool HASZ, bool RELU>
__global__ __launch_bounds__(256) void propw2(const float* __restrict__ X, int xstr,
                                              const float* __restrict__ Z, int zstr,
                                              float* __restrict__ Y, int ystr,
                                              const int* __restrict__ rp,
                                              const int2* __restrict__ e2, int n)
{
    const int NPB = 256 / LPN;
    int node = blockIdx.x * NPB + threadIdx.x / LPN;
    if (node >= n) return;
    int c4 = threadIdx.x % LPN;
    bool colok = (c4 < C4);
    int cq = colok ? c4 : 0;
    int e0 = rp[node], e1 = rp[node + 1];
    float ax = 0.f, ay = 0.f, az = 0.f, aw = 0.f;
    int e = e0;
    for (; e + 8 <= e1; e += 8) {
        int2 q[8];
#pragma unroll
        for (int u = 0; u < 8; u++) q[u] = e2[e + u];
        float4 xq[8];
#pragma unroll
        for (int u = 0; u < 8; u++)
            xq[u] = *(const float4*)(X + (size_t)q[u].x * xstr + 4 * cq);
#pragma unroll
        for (int u = 0; u < 8; u++) {
            float wv = __int_as_float(q[u].y);
            ax += wv * xq[u].x; ay += wv * xq[u].y;
            az += wv * xq[u].z; aw += wv * xq[u].w;
        }
    }
    if (e < e1) {
#pragma unroll
        for (int u = 0; u < 8; u++) {
            int eid = e + u;
            int2 q = (eid < e1) ? e2[eid] : make_int2(0, 0);
            float4 xq = *(const float4*)(X + (size_t)q.x * xstr + 4 * cq);
            float wv = __int_as_float(q.y);
            ax += wv * xq.x; ay += wv * xq.y; az += wv * xq.z; aw += wv * xq.w;
        }
    }
    if (colok) {
        if (HASZ) {
            float4 zq = *(const float4*)(Z + (size_t)node * zstr + 4 * c4);
            ax += zq.x; ay += zq.y; az += zq.z; aw += zq.w;
        }
        if (RELU) {
            ax = fmaxf(ax, 0.f); ay = fmaxf(ay, 0.f);
            az = fmaxf(az, 0.f); aw = fmaxf(aw, 0.f);
        }
        float4 o = { ax, ay, az, aw };
        *(float4*)(Y + (size_t)node * ystr + 4 * c4) = o;
    }
}

// ---------------- fp32 GEMM (L1/L5 odd shapes; R3-proven config) ----------------

__global__ __launch_bounds__(256) void gemm2(
    const float* __restrict__ X, int x_sn, int x_sk,
    const float* __restrict__ W, int w_sk, int w_sc,
    const float* __restrict__ bias,
    float* __restrict__ out, int o_sn, int o_sc,
    int M, int K, int NC, int flags, int bias_cols)
{
    __shared__ float Xs[BK][BM + 4];
    __shared__ float Ws[BK][BN];
    int tid = threadIdx.x;
    int bm = blockIdx.x * BM;
    int bn = blockIdx.y * BN;
    int tx = tid & 15, ty = tid >> 4;
    float acc[8][4] = {};
    int xk = tid & 15, xm = tid >> 4;
    int wc = tid & 63, wk4 = tid >> 6;
    int vr = tid >> 2;
    int vc = (tid & 3) * 4;
    int wvk = tid >> 4;
    int wvc = (tid & 15) * 4;
    bool xvec = (x_sk == 1) && ((x_sn & 3) == 0) && (bm + BM <= M);
    bool wvec = (w_sc == 1) && ((w_sk & 3) == 0) && (bn + BN <= NC);
    for (int k0 = 0; k0 < K; k0 += BK) {
        bool fullk = (k0 + BK <= K);
        if (xvec && fullk) {
#pragma unroll
            for (int h = 0; h < 2; h++) {
                int m = vr + 64 * h;
                const float4 q = *(const float4*)(X + (size_t)(bm + m) * x_sn + k0 + vc);
                Xs[vc + 0][m] = q.x; Xs[vc + 1][m] = q.y;
                Xs[vc + 2][m] = q.z; Xs[vc + 3][m] = q.w;
            }
        } else {
#pragma unroll
            for (int r = 0; r < 8; r++) {
                int m = xm + 16 * r;
                int gm = bm + m, gk = k0 + xk;
                Xs[xk][m] = (gm < M && gk < K) ? X[(size_t)gm * x_sn + (size_t)gk * x_sk] : 0.f;
            }
        }
        if (wvec && fullk) {
            *(float4*)&Ws[wvk][wvc] = *(const float4*)(W + (size_t)(k0 + wvk) * w_sk + bn + wvc);
        } else {
#pragma unroll
            for (int r = 0; r < 4; r++) {
                int kk = wk4 + 4 * r;
                int gk = k0 + kk, gc = bn + wc;
                Ws[kk][wc] = (gk < K && gc < NC) ? W[(size_t)gk * w_sk + (size_t)gc * w_sc] : 0.f;
            }
        }
        __syncthreads();
#pragma unroll
        for (int kk = 0; kk < BK; kk++) {
            float xv[8], wv[4];
#pragma unroll
            for (int i = 0; i < 8; i++) xv[i] = Xs[kk][ty * 8 + i];
#pragma unroll
            for (int j = 0; j < 4; j++) wv[j] = Ws[kk][tx * 4 + j];
#pragma unroll
            for (int i = 0; i < 8; i++)
#pragma unroll
                for (int j = 0; j < 4; j++)
                    acc[i][j] += xv[i] * wv[j];
        }
        __syncthreads();
    }
    bool ovec = (o_sc == 1) && ((o_sn & 3) == 0) && (bn + tx * 4 + 3 < NC);
#pragma unroll
    for (int i = 0; i < 8; i++) {
        int gm = bm + ty * 8 + i;
        if (gm >= M) continue;
        if (ovec) {
            float* op = out + (size_t)gm * o_sn + bn + tx * 4;
            float4 v = { acc[i][0], acc[i][1], acc[i][2], acc[i][3] };
            if (flags & GF_ACC) {
                float4 o = *(const float4*)op;
                v.x += o.x; v.y += o.y; v.z += o.z; v.w += o.w;
            }
            if (flags & GF_BIAS) {
#pragma unroll
                for (int j = 0; j < 4; j++) {
                    int gc = bn + tx * 4 + j;
                    if (gc < bias_cols) (&v.x)[j] += bias[gc];
                }
            }
            if (flags & GF_RELU) {
                v.x = fmaxf(v.x, 0.f); v.y = fmaxf(v.y, 0.f);
                v.z = fmaxf(v.z, 0.f); v.w = fmaxf(v.w, 0.f);
            }
            *(float4*)op = v;
        } else {
#pragma unroll
            for (int j = 0; j < 4; j++) {
                int gc = bn + tx * 4 + j;
                if (gc >= NC) continue;
                size_t oi = (size_t)gm * o_sn + (size_t)gc * o_sc;
                float v = acc[i][j];
                if (flags & GF_ACC)  v += out[oi];
                if ((flags & GF_BIAS) && gc < bias_cols) v += bias[gc];
                if (flags & GF_RELU) v = fmaxf(v, 0.f);
                out[oi] = v;
            }
        }
    }
}

// ---------------- 3-term bf16 split + fragment-ordered W packing ----------------
// Packed layout: idx = (((nb*ksteps + ks)*8 + nt)*3 + plane)*512 + lane*8 + j
// where lane = kq*16 + r, n = nb*128 + nt*16 + r, k = ks*32 + kq*8 + j.

__device__ __forceinline__ void bf16_split3(float v, unsigned short* h,
                                            unsigned short* m, unsigned short* l)
{
    unsigned u = __float_as_uint(v);
    unsigned uh = (u + 0x8000u) & 0xFFFF0000u;
    float fh = __uint_as_float(uh);
    float r1 = v - fh;
    unsigned u1 = __float_as_uint(r1);
    unsigned um = (u1 + 0x8000u) & 0xFFFF0000u;
    float fm = __uint_as_float(um);
    float r2 = r1 - fm;
    unsigned ul = (__float_as_uint(r2) + 0x8000u) & 0xFFFF0000u;
    *h = (unsigned short)(uh >> 16);
    *m = (unsigned short)(um >> 16);
    *l = (unsigned short)(ul >> 16);
}

__device__ __forceinline__ void pack_write(unsigned short* __restrict__ wpk,
                                           int ksteps, int n, int k, float v)
{
    unsigned short h8, m8, l8;
    bf16_split3(v, &h8, &m8, &l8);
    int nb = n >> 7, nn = n & 127;
    int nt = nn >> 4, r = nn & 15;
    int ks = k >> 5, kq = (k >> 3) & 3, j = k & 7;
    int ln = kq * 16 + r;
    size_t base = ((((size_t)nb * ksteps + ks) * 8 + nt) * 3) * 512 + ln * 8 + j;
    wpk[base] = h8;
    wpk[base + 512] = m8;
    wpk[base + 1024] = l8;
}

// W [hops, Cin, Cout] -> packed; k = hop_slot*slot + c, n = cout
__global__ void splitW_stack(const float* __restrict__ Wsrc, int hop0, int H,
                             int Cin, int Cout, int slot, int Kp, int NCp, int ksteps,
                             unsigned short* __restrict__ wpk)
{
    int t = blockIdx.x * blockDim.x + threadIdx.x;
    if (t >= NCp * Kp) return;
    int k = t % Kp, n = t / Kp;
    int j = k / slot, c = k % slot;
    float v = (n < Cout && j < H && c < Cin)
        ? Wsrc[((size_t)(hop0 + j) * Cin + c) * Cout + n] : 0.f;
    pack_write(wpk, ksteps, n, k, v);
}

// W4 [21, 200, 80] -> packed; n = (hop-k_lo)*80 + co, k = cin
__global__ void splitW_horner(const float* __restrict__ W4, int k_lo, int nb,
                              int Kp, int NCp, int ksteps,
                              unsigned short* __restrict__ wpk)
{
    int t = blockIdx.x * blockDim.x + threadIdx.x;
    if (t >= NCp * Kp) return;
    int k = t % Kp, n = t / Kp;
    float v = 0.f;
    if (k < 200 && n < nb * 80) {
        int hop = k_lo + n / 80, co = n % 80;
        v = W4[(size_t)hop * 16000 + (size_t)k * 80 + co];
    }
    pack_write(wpk, ksteps, n, k, v);
}

// ---------------- MFMA GEMM v3: no LDS, 4-wave blocks, register-buffered B ----------------
// 4 waves/block, each wave a 16x128 tile (block = 64 rows). All 24 B fragments
// batched into registers per k-step (one latency exposure); A double-buffered.

__global__ __launch_bounds__(256) void gemm_mfma2(
    const float* __restrict__ X, int x_sn,
    const unsigned short* __restrict__ Wpk, int ksteps,
    const float* __restrict__ bias,
    float* __restrict__ out, int o_sn,
    int M, int NC, int flags, int bias_cols)
{
    int tid = threadIdx.x;
    int w = tid >> 6, lane = tid & 63;
    int r = lane & 15, q = lane >> 4;
    int bm = blockIdx.x * 64 + w * 16;
    int nb = blockIdx.y;
    int bn = nb * 128;
    f32x4 acc[8];
#pragma unroll
    for (int b = 0; b < 8; b++) acc[b] = (f32x4){0.f, 0.f, 0.f, 0.f};
    const float* xrow = X + (size_t)(bm + r) * x_sn + q * 8;
    const unsigned short* wbase = Wpk + (size_t)nb * ksteps * (8 * 3 * 512) + lane * 8;
    float4 fa = *(const float4*)(xrow);
    float4 fb = *(const float4*)(xrow + 4);
    for (int ks = 0; ks < ksteps; ks++) {
        const unsigned short* wk = wbase + (size_t)ks * (8 * 3 * 512);
        bf16x8 bf[8][3];
#pragma unroll
        for (int nt = 0; nt < 8; nt++)
#pragma unroll
            for (int pl = 0; pl < 3; pl++)
                bf[nt][pl] = *(const bf16x8*)(wk + (nt * 3 + pl) * 512);
        float vf[8] = { fa.x, fa.y, fa.z, fa.w, fb.x, fb.y, fb.z, fb.w };
        if (ks + 1 < ksteps) {
            fa = *(const float4*)(xrow + (ks + 1) * 32);
            fb = *(const float4*)(xrow + (ks + 1) * 32 + 4);
        }
        bf16x8 ah, am, al;
#pragma unroll
        for (int j = 0; j < 8; j++) {
            float v = vf[j];
            unsigned u = __float_as_uint(v);
            unsigned uh = u & 0xFFFF0000u;
            float r1 = v - __uint_as_float(uh);
            unsigned u1 = __float_as_uint(r1);
            unsigned um = u1 & 0xFFFF0000u;
            float r2 = r1 - __uint_as_float(um);
            ah[j] = (short)(uh >> 16);
            am[j] = (short)(um >> 16);
            al[j] = (short)(__float_as_uint(r2) >> 16);
        }
#pragma unroll
        for (int nt = 0; nt < 8; nt++) {
            acc[nt] = __builtin_amdgcn_mfma_f32_16x16x32_bf16(al, bf[nt][0], acc[nt], 0, 0, 0);
            acc[nt] = __builtin_amdgcn_mfma_f32_16x16x32_bf16(ah, bf[nt][2], acc[nt], 0, 0, 0);
            acc[nt] = __builtin_amdgcn_mfma_f32_16x16x32_bf16(am, bf[nt][1], acc[nt], 0, 0, 0);
            acc[nt] = __builtin_amdgcn_mfma_f32_16x16x32_bf16(am, bf[nt][0], acc[nt], 0, 0, 0);
            acc[nt] = __builtin_amdgcn_mfma_f32_16x16x32_bf16(ah, bf[nt][1], acc[nt], 0, 0, 0);
            acc[nt] = __builtin_amdgcn_mfma_f32_16x16x32_bf16(ah, bf[nt][0], acc[nt], 0, 0, 0);
        }
    }
#pragma unroll
    for (int i = 0; i < 4; i++) {
        int gm = bm + q * 4 + i;
        if (gm >= M) continue;
#pragma unroll
        for (int nt = 0; nt < 8; nt++) {
            int gc = bn + nt * 16 + r;
            if (gc >= NC) continue;
            size_t oi = (size_t)gm * o_sn + gc;
            float v = acc[nt][i];
            if (flags & GF_ACC)  v += out[oi];
            if ((flags & GF_BIAS) && gc < bias_cols) v += bias[gc];
            if (flags & GF_RELU) v = fmaxf(v, 0.f);
            out[oi] = v;
        }
    }
}

// ---------------- launch ----------------

extern "C" void kernel_launch(void* const* d_in, const int* in_sizes, int n_in,
                              void* d_out, int out_size, void* d_ws, size_t ws_size,
                              hipStream_t stream)
{
    const int N = 50000, E = 800000, K = 20;
    const float* x  = (const float*)d_in[0];
    const int*   ei = (const int*)d_in[1];
    const float* ew = (const float*)d_in[2];
    const float* Wl[5]; const float* bl[5];
    for (int l = 0; l < 5; l++) { Wl[l] = (const float*)d_in[3 + 2 * l]; bl[l] = (const float*)d_in[4 + 2 * l]; }
    const int* src = ei;
    const int* dst = ei + E;
    (void)in_sizes; (void)n_in; (void)out_size;

    uintptr_t base = (uintptr_t)d_ws;
    uintptr_t cur = base;
    auto alloc = [&](size_t bytes) -> char* {
        uintptr_t q = (cur + 255) & ~(uintptr_t)255;
        cur = q + bytes;
        return (char*)q;
    };
    float* deg    = (float*)alloc((size_t)N * 4);
    float* dis    = (float*)alloc((size_t)N * 4);
    int*   rowptr = (int*)alloc((size_t)(N + 1) * 4);
    int*   cursor = (int*)alloc((size_t)N * 4);
    int2*  e2     = (int2*)alloc((size_t)E * 8);
    float* Zb     = (float*)alloc((size_t)(K + 1) * N * 4);  // [21, N] hop-major
    float* ya     = (float*)alloc((size_t)N * 4);
    float* yb     = (float*)alloc((size_t)N * 4);
    float* h1     = (float*)alloc((size_t)N * 64 * 4);   // stride 64 (padded, gathered)
    float* h2     = (float*)alloc((size_t)N * 100 * 4);
    float* h3     = (float*)alloc((size_t)N * 200 * 4);
    float* h4     = (float*)alloc((size_t)N * 80 * 4);
    float* Ra     = (float*)alloc((size_t)N * 96 * 4);   // stride 96 (padded, gathered)
    float* Rb     = (float*)alloc((size_t)N * 96 * 4);

    size_t used = (size_t)(cur - base);
    size_t reserve = (size_t)8 << 20;
    size_t avail = (ws_size > used + reserve) ? (ws_size - used - reserve) : 0;
    size_t cap = (size_t)N * 2000 * 4;
    size_t arena_bytes = avail < cap ? avail : cap;
    float* Sb = (float*)alloc(arena_bytes);
    unsigned short* Wpk = (unsigned short*)alloc((size_t)4 << 20);
    const size_t cacheCap = (size_t)128 << 20;
    size_t lim = arena_bytes < cacheCap ? arena_bytes : cacheCap;
    auto clampH = [&](int slotw, int hi) {
        long h = (long)(lim / ((size_t)N * slotw * 4));
        if (h < 1) h = 1;
        if (h > hi) h = hi;
        return (int)h;
    };
    const int H2s = clampH(64, K);       // -> 10
    const int H3s = clampH(100, K);      // -> 6
    const int B4s = clampH(80, K + 1);   // -> 8
    const int rowstr2 = H2s * 64;
    const int rowstr3 = H3s * 100;
    const int rowstr4 = B4s * 80;

    // ---- CSR build
    hipMemsetAsync(deg, 0, (size_t)N * 4, stream);
    hipMemsetAsync(cursor, 0, (size_t)N * 4, stream);
    deg_count_kernel<<<(E + 255) / 256, 256, 0, stream>>>(src, dst, ew, deg, cursor, E);
    dis_kernel<<<(N + 255) / 256, 256, 0, stream>>>(deg, dis, N);
    scan_kernel<<<1, 1024, 0, stream>>>(cursor, rowptr, N);
    scatter_kernel<<<(E + 255) / 256, 256, 0, stream>>>(src, dst, ew, dis, cursor, e2, E);

    const int PB = (N + 63) / 64;
    const int P16 = (N + 15) / 16;
    const int P32 = (N + 7) / 8;
    const int GMX = (N + BM - 1) / BM;
    const int MT64 = (N + 63) / 64;      // 782 4-wave blocks
    auto gyf = [](int NC) { return (NC + BN - 1) / BN; };

    // ---- Layer 1 (1 -> 60): width-1 chain into Zb, one fp32 GEMM K=21
    hipMemcpyAsync(Zb, x, (size_t)N * 4, hipMemcpyDeviceToDevice, stream);
    for (int k = 1; k <= K; k++)
        prop1<<<PB, 256, 0, stream>>>(Zb + (size_t)(k - 1) * N, nullptr, Zb + (size_t)k * N,
                                      rowptr, e2, N, 0);
    gemm2<<<dim3(GMX, gyf(60)), 256, 0, stream>>>(Zb, 1, N, Wl[0], 60, 1, bl[0],
                                                  h1, 64, 1, N, K + 1, 60, GF_BIAS | GF_RELU, 60);

    // ---- Layer 2 (60 -> 100): h0 via MFMA (Kp=64), hop-batched stack + MFMA
    splitW_stack<<<(128 * 64 + 255) / 256, 256, 0, stream>>>(Wl[1], 0, 1, 60, 100, 64,
                                                             64, 128, 2, Wpk);
    gemm_mfma2<<<dim3(MT64, 1), 256, 0, stream>>>(h1, 64, Wpk, 2,
        bl[1], h2, 100, N, 100, GF_BIAS, 100);
    {
        int done = 0;
        const float* prevp = h1; int prevstr = 64;
        while (done < K) {
            int H = (K - done < H2s) ? (K - done) : H2s;
            for (int j = 0; j < H; j++) {
                float* dstp = Sb + j * 64;
                propw2<16, 15, false, false><<<P16, 256, 0, stream>>>(prevp, prevstr, nullptr, 0,
                    dstp, rowstr2, rowptr, e2, N);
                prevp = dstp; prevstr = rowstr2;
            }
            int Kg = H * 64;                   // multiple of 32
            int ksteps = Kg / 32;
            int tot = 128 * Kg;
            splitW_stack<<<(tot + 255) / 256, 256, 0, stream>>>(Wl[1], 1 + done, H, 60, 100, 64,
                                                               Kg, 128, ksteps, Wpk);
            bool last = (done + H == K);
            gemm_mfma2<<<dim3(MT64, 1), 256, 0, stream>>>(Sb, rowstr2, Wpk, ksteps,
                nullptr, h2, 100, N, 100, GF_ACC | (last ? GF_RELU : 0), 0);
            done += H;
        }
    }

    // ---- Layer 3 (100 -> 200): h0 via MFMA (Kp=128), hop-batched stack + MFMA
    splitW_stack<<<(256 * 128 + 255) / 256, 256, 0, stream>>>(Wl[2], 0, 1, 100, 200, 128,
                                                              128, 256, 4, Wpk);
    gemm_mfma2<<<dim3(MT64, 2), 256, 0, stream>>>(h2, 100, Wpk, 4,
        bl[2], h3, 200, N, 200, GF_BIAS, 200);
    {
        int done = 0;
        const float* prevp = h2; int prevstr = 100;
        while (done < K) {
            int H = (K - done < H3s) ? (K - done) : H3s;
            for (int j = 0; j < H; j++) {
                float* dstp = Sb + j * 100;
                propw2<32, 25, false, false><<<P32, 256, 0, stream>>>(prevp, prevstr, nullptr, 0,
                    dstp, rowstr3, rowptr, e2, N);
                prevp = dstp; prevstr = rowstr3;
            }
            int Kg = H * 100;
            int Kp = (Kg + 31) & ~31;
            int ksteps = Kp / 32;
            int tot = 256 * Kp;
            splitW_stack<<<(tot + 255) / 256, 256, 0, stream>>>(Wl[2], 1 + done, H, 100, 200, 100,
                                                               Kp, 256, ksteps, Wpk);
            bool last = (done + H == K);
            gemm_mfma2<<<dim3(MT64, 2), 256, 0, stream>>>(Sb, rowstr3, Wpk, ksteps,
                nullptr, h3, 200, N, 200, GF_ACC | (last ? GF_RELU : 0), 0);
            done += H;
        }
    }

    // ---- Layer 4 (200 -> 80): batched Z pre-GEMM (MFMA) + Horner width-80
    {
        const float* curR = nullptr; int curstr = 0;
        int k_hi = K;
        while (k_hi >= 0) {
            int k_lo = k_hi - B4s + 1; if (k_lo < 0) k_lo = 0;
            int nb = k_hi - k_lo + 1;
            int NCpb = (nb * 80 + 127) / 128;
            int NCp = NCpb * 128;
            int tot = NCp * 224;
            splitW_horner<<<(tot + 255) / 256, 256, 0, stream>>>(Wl[3], k_lo, nb,
                                                                 224, NCp, 7, Wpk);
            gemm_mfma2<<<dim3(MT64, NCpb), 256, 0, stream>>>(h3, 200, Wpk, 7,
                bl[3], Sb, rowstr4, N, nb * 80, (k_lo == 0) ? GF_BIAS : 0, 80);
            int kstart;
            if (k_hi == K) { curR = Sb + (size_t)(K - k_lo) * 80; curstr = rowstr4; kstart = K - 1; }
            else kstart = k_hi;
            for (int k = kstart; k >= k_lo; k--) {
                const float* Zp = Sb + (size_t)(k - k_lo) * 80;
                if (k == 0) {
                    propw2<32, 20, true, true><<<P32, 256, 0, stream>>>(curR, curstr, Zp, rowstr4,
                        h4, 80, rowptr, e2, N);
                } else {
                    float* o = (k & 1) ? Ra : Rb;
                    propw2<32, 20, true, false><<<P32, 256, 0, stream>>>(curR, curstr, Zp, rowstr4,
                        o, 96, rowptr, e2, N);
                    curR = o; curstr = 96;
                }
            }
            k_hi = k_lo - 1;
        }
    }

    // ---- Layer 5 (80 -> 1): Z5 [21, N] hop-major, Horner width-1 with sigmoid
    gemm2<<<dim3(GMX, gyf(21)), 256, 0, stream>>>(h4, 80, 1, Wl[4], 1, 80, bl[4],
                                                  Zb, 1, N, N, 80, K + 1, GF_BIAS, 1);
    const float* cur5 = Zb + (size_t)K * N;
    float* outp = (float*)d_out;
    for (int k = K - 1; k >= 0; k--) {
        float* o = (k == 0) ? outp : ((k & 1) ? ya : yb);
        prop1<<<PB, 256, 0, stream>>>(cur5, Zb + (size_t)k * N, o,
                                      rowptr, e2, N, (k == 0) ? 1 : 0);
        cur5 = o;
    }
}